// Round 9
// baseline (113.293 us; speedup 1.0000x reference)
//
#include <hip/hip_runtime.h>

// SlidingKernelAttention: unfold(k=4,s=1) -> per-(b,c,patch-offset) attention
// over seq=256 tokens of dim=16 -> overlap-add fold.
// B=2, C=64, H=W=67, Ho=Wo=64, N = B*C*16 = 2048 independent sequences.
//
// R18 = R17 with (a) atomic-free merge and (b) a REP=3 diagnostic.
// R17 post-mortem: total 80.8 (best), fused kernel ~39us but still below
// the ~41us d_ws fills -> no counters. Issue arithmetic says ~16us; the
// ~23us residual's new suspect is the epilogue's 2.2M global atomicAdds
// (L2 RMW). This round:
//  (a) kernel1 stores each block's 64x67 f32 partial to d_ws with PLAIN
//      coalesced stores ([bc][ii][64][67], 8.7MB); kernel2 sums the <=4
//      valid partials per out element (11MB traffic, ~2-3us). No global
//      atomics, no out-memset.
//  (b) REP=3 on the attention loop (same l/oacc accumulation; softmax
//      normalization is invariant under o->3o, l->3l; asm guard on qfr
//      blocks CSE) so kernel1 (~55us) OUTRANKS the fills and we finally
//      read VGPR/VALUBusy/MfmaUtil/Occupancy for the fused structure.
//      R19 reverts REP. Read: P_res = dur(kernel1) - 33us (M=11us/rep,
//      R12). P_res<=10 -> atomics were R17's residual; P_res~25 -> the
//      residual survives, localize with the counters.
//
// Structure (R17): block=(bc,ii), 512 blocks x 512 thr (2/CU), 4 planes
// (jj) serial per block, R15 cross-plane x-prefetch, KV double-buffered
// LDS (2x16KB), one barrier/plane, R11 2-q-tile main loop, wave-private
// fold rows (r=8*wave+4u+(o>>2) in [8w,8w+8)) -> plain LDS += (no
// atomics anywhere now). LDS 49.7KB/block.
//
// MFMA layout identity (R5-R8): projection MFMA results ARE attention
// operands (K^T/V A-frags, Q^T/P^T B-frags). Fold mapping (HW-verified
// R16/R17): query q=jq*16+o, feature idx of plane (ii,jj) adds to
// out[bc][4*jq+(o>>2)+ii][16*(o&3)+4*g+idx+jj]; partial[bc][ii][r][c]
// contributes to out[bc][r+ii][c]. All fragments statically indexed (R4);
// f16 via v_cvt_pkrtz + bit_cast/shufflevector only (R8).
// Timed window includes the ~41-50us harness fill of d_ws (unavoidable;
// runs even if d_ws unused - R16).

#define BATCH 2
#define CHAN 64
#define HWDIM 67
#define SEQ 256
#define DIM 16
#define OUT_TOTAL (BATCH * CHAN * HWDIM * HWDIM)   // 574592
#define ATT_SCALE 0.70710678118654752f             // (DIM/HEADS)^-0.5
#define LOG2E 1.44269504088896340736f
#define REP 3                // diagnostic main-loop repetition (see header)

typedef _Float16 half4 __attribute__((ext_vector_type(4)));
typedef _Float16 half8 __attribute__((ext_vector_type(8)));
typedef float float4v __attribute__((ext_vector_type(4)));
typedef __fp16 fp16x2 __attribute__((ext_vector_type(2)));
typedef unsigned int uint2v __attribute__((ext_vector_type(2)));

// 2x v_cvt_pkrtz + register-pair aliasing: zero insert/extract VALU.
static __device__ __forceinline__ half4 mk_half4(float a, float b, float c, float d) {
    fp16x2 lo = __builtin_amdgcn_cvt_pkrtz(a, b);
    fp16x2 hi = __builtin_amdgcn_cvt_pkrtz(c, d);
    uint2v u;
    u[0] = __builtin_bit_cast(unsigned int, lo);
    u[1] = __builtin_bit_cast(unsigned int, hi);
    return __builtin_bit_cast(half4, u);
}

static __device__ __forceinline__ half4 pack4(float4v c) {
    return mk_half4(c[0], c[1], c[2], c[3]);
}

// one q-tile step: exp2 the 4 scores, accumulate denominator, pack,
// accumulate O^T.
static __device__ __forceinline__ void att_step(const half4 vf, const float4v sfr,
                                                float& l, float4v& oacc) {
    const float p0 = __builtin_amdgcn_exp2f(sfr[0]);
    const float p1 = __builtin_amdgcn_exp2f(sfr[1]);
    const float p2 = __builtin_amdgcn_exp2f(sfr[2]);
    const float p3 = __builtin_amdgcn_exp2f(sfr[3]);
    l += (p0 + p1) + (p2 + p3);
    const half4 pb = mk_half4(p0, p1, p2, p3);
    oacc = __builtin_amdgcn_mfma_f32_16x16x16f16(vf, pb, oacc, 0, 0, 0);
}

__global__ __launch_bounds__(512, 4) void ska_part(
    const float* __restrict__ x,      // [B, C, 67, 67]
    const float* __restrict__ w,      // [48, 16]
    float* __restrict__ partial)      // [B*C, 4, 64, 67] in d_ws
{
    __shared__ __align__(16) _Float16 buf[2][16][64][8];   // 32 KB KV dbuf
    __shared__ float fold[64][69];                          // 17.7 KB

    // XCD chunked swizzle: 512 blocks = 8 XCDs x 64 -> bc [16k,16k+16) on
    // XCD k; the 4 blocks of a bc share x[bc] (18KB) in one XCD's L2.
    const int b  = (int)(blockIdx.x & 7) * 64 + (int)(blockIdx.x >> 3);
    const int bc = b >> 2;
    const int ii = b & 3;          // patch-row offset of this block's planes

    const int tid  = threadIdx.x;
    const int wave = tid >> 6;     // 0..7: owns q/k tiles 2w, 2w+1
    const int lane = tid & 63;
    const int o = lane & 15;       // token-in-tile / weight output row
    const int g = lane >> 4;       // feature group (k-group)

    // zero the fold tile (first KV barrier below orders this before the
    // round-0 fold writes)
    {
        float* ff = &fold[0][0];
        for (int i = tid; i < 64 * 69; i += 512) ff[i] = 0.f;
    }

    // weight fragments straight from global (3 KB, L1-resident)
    const float4 wq4 = *(const float4*)(w + ( 0 + o) * DIM + 4 * g);
    const float4 wk4 = *(const float4*)(w + (16 + o) * DIM + 4 * g);
    const float4 wv4 = *(const float4*)(w + (32 + o) * DIM + 4 * g);
    const half4 wqf = mk_half4(wq4.x * (ATT_SCALE * LOG2E), wq4.y * (ATT_SCALE * LOG2E),
                               wq4.z * (ATT_SCALE * LOG2E), wq4.w * (ATT_SCALE * LOG2E));
    const half4 wkf = mk_half4(wk4.x, wk4.y, wk4.z, wk4.w);
    const half4 wvf = mk_half4(wv4.x, wv4.y, wv4.z, wv4.w);

    const float4v zf = (float4v){0.f, 0.f, 0.f, 0.f};

    // X addressing (R13/R15, HW-verified): lane (o,g) of tile t of plane
    // (ii,jj) holds features 4g..4g+3 of token s=t*16+o:
    //   x[bc][4t + (o>>2) + ii][16*(o&3) + 4g + jj .. +3]
    const float* xb = x + ((size_t)bc * HWDIM + ii) * HWDIM + (o & 3) * 16 + 4 * g;
    const int roff0 = (8 * wave + (o >> 2)) * HWDIM;
    const int roff1 = roff0 + 4 * HWDIM;

    // prefetch plane jj=0 (scalar loads; jj>0 addresses are 4B-aligned)
    float xr0a = xb[roff0 + 0], xr0b = xb[roff0 + 1],
          xr0c = xb[roff0 + 2], xr0d = xb[roff0 + 3];
    float xr1a = xb[roff1 + 0], xr1b = xb[roff1 + 1],
          xr1c = xb[roff1 + 2], xr1d = xb[roff1 + 3];

    for (int jj = 0; jj < 4; ++jj) {
        const int cur = jj & 1;

        // projection for plane jj from the prefetched x registers
        half4 qfr0, qfr1;
        {
            const half4 xf0 = mk_half4(xr0a, xr0b, xr0c, xr0d);
            const half4 kf0 = pack4(__builtin_amdgcn_mfma_f32_16x16x16f16(wkf, xf0, zf, 0, 0, 0));
            const half4 vf0 = pack4(__builtin_amdgcn_mfma_f32_16x16x16f16(xf0, wvf, zf, 0, 0, 0));
            *(half8*)&buf[cur][2 * wave][lane][0] =
                __builtin_shufflevector(kf0, vf0, 0, 1, 2, 3, 4, 5, 6, 7);
            qfr0 = pack4(__builtin_amdgcn_mfma_f32_16x16x16f16(wqf, xf0, zf, 0, 0, 0));

            const half4 xf1 = mk_half4(xr1a, xr1b, xr1c, xr1d);
            const half4 kf1 = pack4(__builtin_amdgcn_mfma_f32_16x16x16f16(wkf, xf1, zf, 0, 0, 0));
            const half4 vf1 = pack4(__builtin_amdgcn_mfma_f32_16x16x16f16(xf1, wvf, zf, 0, 0, 0));
            *(half8*)&buf[cur][2 * wave + 1][lane][0] =
                __builtin_shufflevector(kf1, vf1, 0, 1, 2, 3, 4, 5, 6, 7);
            qfr1 = pack4(__builtin_amdgcn_mfma_f32_16x16x16f16(wqf, xf1, zf, 0, 0, 0));
        }

        // issue next plane's x loads now (+1 column); consumed after this
        // plane's main loop -> latency hides under the compute below.
        if (jj < 3) {
            const int d = jj + 1;
            xr0a = xb[roff0 + d + 0]; xr0b = xb[roff0 + d + 1];
            xr0c = xb[roff0 + d + 2]; xr0d = xb[roff0 + d + 3];
            xr1a = xb[roff1 + d + 0]; xr1b = xb[roff1 + d + 1];
            xr1c = xb[roff1 + d + 2]; xr1d = xb[roff1 + d + 3];
        }

        __syncthreads();   // kv frags of plane jj ready (one barrier/plane)

        float4v oacc0 = zf, oacc1 = zf;
        float l0 = 0.f, l1 = 0.f;

        // DIAGNOSTIC REP: identical main loop x3 into the same l/oacc;
        // softmax cancels the 3x exactly. asm guard defeats CSE.
        for (int rep = 0; rep < REP; ++rep) {
            asm volatile("" : "+v"(qfr0), "+v"(qfr1));
            half8 kvc = *(const half8*)&buf[cur][0][lane][0];
#pragma unroll 4
            for (int t = 0; t < 16; ++t) {
                const half8 kvn = *(const half8*)&buf[cur][(t + 1) & 15][lane][0];
                const half4 kf = __builtin_shufflevector(kvc, kvc, 0, 1, 2, 3);
                const half4 vf = __builtin_shufflevector(kvc, kvc, 4, 5, 6, 7);
                const float4v s0 = __builtin_amdgcn_mfma_f32_16x16x16f16(kf, qfr0, zf, 0, 0, 0);
                const float4v s1 = __builtin_amdgcn_mfma_f32_16x16x16f16(kf, qfr1, zf, 0, 0, 0);
                att_step(vf, s0, l0, oacc0);
                att_step(vf, s1, l1, oacc1);
                kvc = kvn;
            }
        }

        // denom reduce + fold. Fold rows r = 8*wave+4u+(o>>2) are
        // wave-private -> plain += (no atomics).
#pragma unroll
        for (int u = 0; u < 2; ++u) {
            float lj = u ? l1 : l0;
            lj += __shfl_xor(lj, 16, 64);
            lj += __shfl_xor(lj, 32, 64);
            const float rl = __builtin_amdgcn_rcpf(lj);
            const float4v oa = u ? oacc1 : oacc0;
            const int r = 8 * wave + 4 * u + (o >> 2);
            const int c = 16 * (o & 3) + 4 * g + jj;
            fold[r][c + 0] += oa[0] * rl;
            fold[r][c + 1] += oa[1] * rl;
            fold[r][c + 2] += oa[2] * rl;
            fold[r][c + 3] += oa[3] * rl;
        }
        // no trailing barrier: next projection writes buf[(jj+1)&1];
        // buf[jj&1] reused only after the NEXT barrier (hazard-free, R15).
    }

    __syncthreads();   // all planes folded

    // plain coalesced store of this block's partial (NO atomics)
    float* pb = partial + ((size_t)(bc * 4 + ii)) * (64 * HWDIM);
    for (int i = tid; i < 64 * HWDIM; i += 512) {
        pb[i] = fold[i / HWDIM][i % HWDIM];
    }
}

// kernel2: out[bc][h][w] = sum over ii of partial[bc][ii][h-ii][w]
// (valid when 0 <= h-ii < 64). 11MB traffic, memory-bound.
__global__ __launch_bounds__(256) void ska_sum(
    const float* __restrict__ partial,
    float* __restrict__ out)
{
    const int idx = (int)(blockIdx.x * 256 + threadIdx.x);
    if (idx >= OUT_TOTAL) return;
    const int bc  = idx / (HWDIM * HWDIM);
    const int rem = idx % (HWDIM * HWDIM);
    const int h   = rem / HWDIM;
    const int ww  = rem % HWDIM;
    float acc = 0.f;
#pragma unroll
    for (int ii = 0; ii < 4; ++ii) {
        const int r = h - ii;
        if (r >= 0 && r < 64)
            acc += partial[((size_t)(bc * 4 + ii)) * (64 * HWDIM) + r * HWDIM + ww];
    }
    out[idx] = acc;
}

// ---- fallback (R17 atomic merge) if workspace is too small ----
__global__ __launch_bounds__(512, 4) void ska_fused_atomic(
    const float* __restrict__ x, const float* __restrict__ w,
    float* __restrict__ out)
{
    __shared__ __align__(16) _Float16 buf[2][16][64][8];
    __shared__ float fold[64][69];

    const int b  = (int)(blockIdx.x & 7) * 64 + (int)(blockIdx.x >> 3);
    const int bc = b >> 2;
    const int ii = b & 3;
    const int tid  = threadIdx.x;
    const int wave = tid >> 6;
    const int lane = tid & 63;
    const int o = lane & 15;
    const int g = lane >> 4;

    {
        float* ff = &fold[0][0];
        for (int i = tid; i < 64 * 69; i += 512) ff[i] = 0.f;
    }

    const float4 wq4 = *(const float4*)(w + ( 0 + o) * DIM + 4 * g);
    const float4 wk4 = *(const float4*)(w + (16 + o) * DIM + 4 * g);
    const float4 wv4 = *(const float4*)(w + (32 + o) * DIM + 4 * g);
    const half4 wqf = mk_half4(wq4.x * (ATT_SCALE * LOG2E), wq4.y * (ATT_SCALE * LOG2E),
                               wq4.z * (ATT_SCALE * LOG2E), wq4.w * (ATT_SCALE * LOG2E));
    const half4 wkf = mk_half4(wk4.x, wk4.y, wk4.z, wk4.w);
    const half4 wvf = mk_half4(wv4.x, wv4.y, wv4.z, wv4.w);
    const float4v zf = (float4v){0.f, 0.f, 0.f, 0.f};

    const float* xb = x + ((size_t)bc * HWDIM + ii) * HWDIM + (o & 3) * 16 + 4 * g;
    const int roff0 = (8 * wave + (o >> 2)) * HWDIM;
    const int roff1 = roff0 + 4 * HWDIM;

    float xr0a = xb[roff0 + 0], xr0b = xb[roff0 + 1],
          xr0c = xb[roff0 + 2], xr0d = xb[roff0 + 3];
    float xr1a = xb[roff1 + 0], xr1b = xb[roff1 + 1],
          xr1c = xb[roff1 + 2], xr1d = xb[roff1 + 3];

    for (int jj = 0; jj < 4; ++jj) {
        const int cur = jj & 1;
        half4 qfr0, qfr1;
        {
            const half4 xf0 = mk_half4(xr0a, xr0b, xr0c, xr0d);
            const half4 kf0 = pack4(__builtin_amdgcn_mfma_f32_16x16x16f16(wkf, xf0, zf, 0, 0, 0));
            const half4 vf0 = pack4(__builtin_amdgcn_mfma_f32_16x16x16f16(xf0, wvf, zf, 0, 0, 0));
            *(half8*)&buf[cur][2 * wave][lane][0] =
                __builtin_shufflevector(kf0, vf0, 0, 1, 2, 3, 4, 5, 6, 7);
            qfr0 = pack4(__builtin_amdgcn_mfma_f32_16x16x16f16(wqf, xf0, zf, 0, 0, 0));
            const half4 xf1 = mk_half4(xr1a, xr1b, xr1c, xr1d);
            const half4 kf1 = pack4(__builtin_amdgcn_mfma_f32_16x16x16f16(wkf, xf1, zf, 0, 0, 0));
            const half4 vf1 = pack4(__builtin_amdgcn_mfma_f32_16x16x16f16(xf1, wvf, zf, 0, 0, 0));
            *(half8*)&buf[cur][2 * wave + 1][lane][0] =
                __builtin_shufflevector(kf1, vf1, 0, 1, 2, 3, 4, 5, 6, 7);
            qfr1 = pack4(__builtin_amdgcn_mfma_f32_16x16x16f16(wqf, xf1, zf, 0, 0, 0));
        }
        if (jj < 3) {
            const int d = jj + 1;
            xr0a = xb[roff0 + d + 0]; xr0b = xb[roff0 + d + 1];
            xr0c = xb[roff0 + d + 2]; xr0d = xb[roff0 + d + 3];
            xr1a = xb[roff1 + d + 0]; xr1b = xb[roff1 + d + 1];
            xr1c = xb[roff1 + d + 2]; xr1d = xb[roff1 + d + 3];
        }
        __syncthreads();

        float4v oacc0 = zf, oacc1 = zf;
        float l0 = 0.f, l1 = 0.f;
        half8 kvc = *(const half8*)&buf[cur][0][lane][0];
#pragma unroll 4
        for (int t = 0; t < 16; ++t) {
            const half8 kvn = *(const half8*)&buf[cur][(t + 1) & 15][lane][0];
            const half4 kf = __builtin_shufflevector(kvc, kvc, 0, 1, 2, 3);
            const half4 vf = __builtin_shufflevector(kvc, kvc, 4, 5, 6, 7);
            const float4v s0 = __builtin_amdgcn_mfma_f32_16x16x16f16(kf, qfr0, zf, 0, 0, 0);
            const float4v s1 = __builtin_amdgcn_mfma_f32_16x16x16f16(kf, qfr1, zf, 0, 0, 0);
            att_step(vf, s0, l0, oacc0);
            att_step(vf, s1, l1, oacc1);
            kvc = kvn;
        }
#pragma unroll
        for (int u = 0; u < 2; ++u) {
            float lj = u ? l1 : l0;
            lj += __shfl_xor(lj, 16, 64);
            lj += __shfl_xor(lj, 32, 64);
            const float rl = __builtin_amdgcn_rcpf(lj);
            const float4v oa = u ? oacc1 : oacc0;
            const int r = 8 * wave + 4 * u + (o >> 2);
            const int c = 16 * (o & 3) + 4 * g + jj;
            fold[r][c + 0] += oa[0] * rl;
            fold[r][c + 1] += oa[1] * rl;
            fold[r][c + 2] += oa[2] * rl;
            fold[r][c + 3] += oa[3] * rl;
        }
    }
    __syncthreads();

    float* ob = out + ((size_t)bc * HWDIM + ii) * HWDIM;
    for (int i = tid; i < 64 * HWDIM; i += 512) {
        atomicAdd(&ob[i], fold[i / HWDIM][i % HWDIM]);
    }
}

extern "C" void kernel_launch(void* const* d_in, const int* in_sizes, int n_in,
                              void* d_out, int out_size, void* d_ws, size_t ws_size,
                              hipStream_t stream) {
    const float* x = (const float*)d_in[0];
    const float* w = (const float*)d_in[1];
    float* out = (float*)d_out;
    (void)in_sizes; (void)n_in;

    const size_t need = (size_t)BATCH * CHAN * 4 * 64 * HWDIM * sizeof(float); // 8.8 MB
    if (ws_size >= need) {
        float* partial = (float*)d_ws;
        ska_part<<<BATCH * CHAN * 4, 512, 0, stream>>>(x, w, partial);
        ska_sum<<<(OUT_TOTAL + 255) / 256, 256, 0, stream>>>(partial, out);
    } else {
        (void)hipMemsetAsync(out, 0, (size_t)out_size * sizeof(float), stream);
        ska_fused_atomic<<<BATCH * CHAN * 4, 512, 0, stream>>>(x, w, out);
    }
}

// Round 10
// 87.072 us; speedup vs baseline: 1.3011x; 1.3011x over previous
//
#include <hip/hip_runtime.h>

// SlidingKernelAttention: unfold(k=4,s=1) -> per-(b,c,patch-offset) attention
// over seq=256 tokens of dim=16 -> overlap-add fold.
// B=2, C=64, H=W=67, Ho=Wo=64, N = B*C*16 = 2048 independent sequences.
//
// R19: occupancy 4 blocks/CU. R18's REP=3 counters finally closed the
// model: VALUBusy 63.7% x 64.5us = 41us busy == 2.1M wave64 exp2/rep x 3
// x ~12cyc / 1024 SIMD (31us) + ~10us VALU. The kernel is trans/VALU-
// issue-bound at 4 waves/SIMD with 37% issue bubbles (dependent
// S-MFMA->exp2->pack->O-MFMA chains). The old "P=25us" was never a
// phase - it's bubbles, which is why deleting/pipelining prologue work
// (R13/R15/R18a) was null. Fix: 8 waves/SIMD.
//   - single KV buffer (16KB, was 32KB dbuf) + fold 17.7KB = 33.7KB/block
//     -> 4 blocks/CU (LDS- and thread-capped equally).
//   - block = (bc, ii, jh): 1024 blocks x 512 thr, 2 planes (jj=2jh,2jh+1)
//     serial per block; 2 barriers/plane (2nd replaces the dbuf).
//   - __launch_bounds__(512,8) pins 8 waves/SIMD (VGPR<=64; engine
//     measured 48). 4 independently-phased blocks/CU fill each other's
//     bubbles.
//   - REP reverted to 1. Atomic-free merge kept: partial[bc][ii][jh]
//     (8 per bc, 17.6MB), ska_sum reads 8 partials (~21MB, ~3.5us).
//
// MFMA layout identity (R5-R8): projection MFMA results ARE attention
// operands (K^T/V A-frags, Q^T/P^T B-frags). Fold mapping (HW-verified
// R16-R18): query q=jq*16+o, feature idx of plane (ii,jj) adds to
// fold[4*jq+(o>>2)][16*(o&3)+4*g+idx+jj]; fold rows r=8*wave+4u+(o>>2)
// are wave-private -> plain += (no atomics). partial[bc][ii][jh][r][c]
// contributes to out[bc][r+ii][c]. All fragments statically indexed (R4);
// f16 via v_cvt_pkrtz + bit_cast/shufflevector only (R8).
// Timed window includes the ~41-50us harness fill of d_ws (unavoidable;
// runs even if d_ws unused - R16).

#define BATCH 2
#define CHAN 64
#define HWDIM 67
#define SEQ 256
#define DIM 16
#define OUT_TOTAL (BATCH * CHAN * HWDIM * HWDIM)   // 574592
#define ATT_SCALE 0.70710678118654752f             // (DIM/HEADS)^-0.5
#define LOG2E 1.44269504088896340736f
#define PSTRIDE (64 * HWDIM)                       // 4288 floats per partial

typedef _Float16 half4 __attribute__((ext_vector_type(4)));
typedef _Float16 half8 __attribute__((ext_vector_type(8)));
typedef float float4v __attribute__((ext_vector_type(4)));
typedef __fp16 fp16x2 __attribute__((ext_vector_type(2)));
typedef unsigned int uint2v __attribute__((ext_vector_type(2)));

// 2x v_cvt_pkrtz + register-pair aliasing: zero insert/extract VALU.
static __device__ __forceinline__ half4 mk_half4(float a, float b, float c, float d) {
    fp16x2 lo = __builtin_amdgcn_cvt_pkrtz(a, b);
    fp16x2 hi = __builtin_amdgcn_cvt_pkrtz(c, d);
    uint2v u;
    u[0] = __builtin_bit_cast(unsigned int, lo);
    u[1] = __builtin_bit_cast(unsigned int, hi);
    return __builtin_bit_cast(half4, u);
}

static __device__ __forceinline__ half4 pack4(float4v c) {
    return mk_half4(c[0], c[1], c[2], c[3]);
}

// one q-tile step: exp2 the 4 scores, accumulate denominator, pack,
// accumulate O^T.
static __device__ __forceinline__ void att_step(const half4 vf, const float4v sfr,
                                                float& l, float4v& oacc) {
    const float p0 = __builtin_amdgcn_exp2f(sfr[0]);
    const float p1 = __builtin_amdgcn_exp2f(sfr[1]);
    const float p2 = __builtin_amdgcn_exp2f(sfr[2]);
    const float p3 = __builtin_amdgcn_exp2f(sfr[3]);
    l += (p0 + p1) + (p2 + p3);
    const half4 pb = mk_half4(p0, p1, p2, p3);
    oacc = __builtin_amdgcn_mfma_f32_16x16x16f16(vf, pb, oacc, 0, 0, 0);
}

__global__ __launch_bounds__(512, 8) void ska_part(
    const float* __restrict__ x,      // [B, C, 67, 67]
    const float* __restrict__ w,      // [48, 16]
    float* __restrict__ partial)      // [B*C, 4, 2, 64, 67] in d_ws
{
    __shared__ __align__(16) _Float16 buf[16][64][8];   // 16 KB KV (single)
    __shared__ float fold[64][69];                       // 17.7 KB

    // XCD chunked swizzle: 1024 blocks = 8 XCDs x 128 -> bc [16k,16k+16)
    // on XCD k. b -> (bc, ii, jh): 8 blocks per bc.
    const int b  = (int)(blockIdx.x & 7) * 128 + (int)(blockIdx.x >> 3);
    const int bc = b >> 3;
    const int ii = (b >> 1) & 3;   // patch-row offset
    const int jh = b & 1;          // jj-half: planes jj = 2*jh, 2*jh+1

    const int tid  = threadIdx.x;
    const int wave = tid >> 6;     // 0..7: owns q/k tiles 2w, 2w+1
    const int lane = tid & 63;
    const int o = lane & 15;       // token-in-tile / weight output row
    const int g = lane >> 4;       // feature group (k-group)

    // zero the fold tile (barrier A below orders this before fold writes)
    {
        float* ff = &fold[0][0];
        for (int i = tid; i < 64 * 69; i += 512) ff[i] = 0.f;
    }

    // weight fragments straight from global (3 KB, L1-resident)
    const float4 wq4 = *(const float4*)(w + ( 0 + o) * DIM + 4 * g);
    const float4 wk4 = *(const float4*)(w + (16 + o) * DIM + 4 * g);
    const float4 wv4 = *(const float4*)(w + (32 + o) * DIM + 4 * g);
    const half4 wqf = mk_half4(wq4.x * (ATT_SCALE * LOG2E), wq4.y * (ATT_SCALE * LOG2E),
                               wq4.z * (ATT_SCALE * LOG2E), wq4.w * (ATT_SCALE * LOG2E));
    const half4 wkf = mk_half4(wk4.x, wk4.y, wk4.z, wk4.w);
    const half4 wvf = mk_half4(wv4.x, wv4.y, wv4.z, wv4.w);

    const float4v zf = (float4v){0.f, 0.f, 0.f, 0.f};

    // X addressing (R13/R15, HW-verified): lane (o,g) of tile t of plane
    // (ii,jj) holds features 4g..4g+3 of token s=t*16+o:
    //   x[bc][4t + (o>>2) + ii][16*(o&3) + 4g + jj .. +3]
    const float* xb = x + ((size_t)bc * HWDIM + ii) * HWDIM + (o & 3) * 16 + 4 * g;
    const int roff0 = (8 * wave + (o >> 2)) * HWDIM;
    const int roff1 = roff0 + 4 * HWDIM;

    // prefetch first plane jj=2*jh (scalar loads; odd jj is 4B-aligned)
    const int jj0 = 2 * jh;
    float xr0a = xb[roff0 + jj0 + 0], xr0b = xb[roff0 + jj0 + 1],
          xr0c = xb[roff0 + jj0 + 2], xr0d = xb[roff0 + jj0 + 3];
    float xr1a = xb[roff1 + jj0 + 0], xr1b = xb[roff1 + jj0 + 1],
          xr1c = xb[roff1 + jj0 + 2], xr1d = xb[roff1 + jj0 + 3];

    for (int pp = 0; pp < 2; ++pp) {
        const int jj = jj0 + pp;

        // projection for plane jj from the prefetched x registers
        half4 qfr0, qfr1;
        {
            const half4 xf0 = mk_half4(xr0a, xr0b, xr0c, xr0d);
            const half4 kf0 = pack4(__builtin_amdgcn_mfma_f32_16x16x16f16(wkf, xf0, zf, 0, 0, 0));
            const half4 vf0 = pack4(__builtin_amdgcn_mfma_f32_16x16x16f16(xf0, wvf, zf, 0, 0, 0));
            *(half8*)&buf[2 * wave][lane][0] =
                __builtin_shufflevector(kf0, vf0, 0, 1, 2, 3, 4, 5, 6, 7);
            qfr0 = pack4(__builtin_amdgcn_mfma_f32_16x16x16f16(wqf, xf0, zf, 0, 0, 0));

            const half4 xf1 = mk_half4(xr1a, xr1b, xr1c, xr1d);
            const half4 kf1 = pack4(__builtin_amdgcn_mfma_f32_16x16x16f16(wkf, xf1, zf, 0, 0, 0));
            const half4 vf1 = pack4(__builtin_amdgcn_mfma_f32_16x16x16f16(xf1, wvf, zf, 0, 0, 0));
            *(half8*)&buf[2 * wave + 1][lane][0] =
                __builtin_shufflevector(kf1, vf1, 0, 1, 2, 3, 4, 5, 6, 7);
            qfr1 = pack4(__builtin_amdgcn_mfma_f32_16x16x16f16(wqf, xf1, zf, 0, 0, 0));
        }

        // issue next plane's x loads (+1 column) now; consumed after this
        // plane's main loop -> latency hides under the compute.
        if (pp == 0) {
            const int d = jj0 + 1;
            xr0a = xb[roff0 + d + 0]; xr0b = xb[roff0 + d + 1];
            xr0c = xb[roff0 + d + 2]; xr0d = xb[roff0 + d + 3];
            xr1a = xb[roff1 + d + 0]; xr1b = xb[roff1 + d + 1];
            xr1c = xb[roff1 + d + 2]; xr1d = xb[roff1 + d + 3];
        }

        __syncthreads();   // barrier A/C: kv frags ready (also orders the
                           // fold zeroing before round-0 fold writes)

        float4v oacc0 = zf, oacc1 = zf;
        float l0 = 0.f, l1 = 0.f;

        // main loop: one ds_read_b128 per k-tile, prefetched one tile
        // ahead; 2 S-MFMAs issue before the exp2/pack/O-MFMA phase.
        half8 kvc = *(const half8*)&buf[0][lane][0];
#pragma unroll 4
        for (int t = 0; t < 16; ++t) {
            const half8 kvn = *(const half8*)&buf[(t + 1) & 15][lane][0];
            const half4 kf = __builtin_shufflevector(kvc, kvc, 0, 1, 2, 3);
            const half4 vf = __builtin_shufflevector(kvc, kvc, 4, 5, 6, 7);
            const float4v s0 = __builtin_amdgcn_mfma_f32_16x16x16f16(kf, qfr0, zf, 0, 0, 0);
            const float4v s1 = __builtin_amdgcn_mfma_f32_16x16x16f16(kf, qfr1, zf, 0, 0, 0);
            att_step(vf, s0, l0, oacc0);
            att_step(vf, s1, l1, oacc1);
            kvc = kvn;
        }

        // denom reduce + fold. Fold rows r = 8*wave+4u+(o>>2) are
        // wave-private -> plain += (no atomics).
#pragma unroll
        for (int u = 0; u < 2; ++u) {
            float lj = u ? l1 : l0;
            lj += __shfl_xor(lj, 16, 64);
            lj += __shfl_xor(lj, 32, 64);
            const float rl = __builtin_amdgcn_rcpf(lj);
            const float4v oa = u ? oacc1 : oacc0;
            const int r = 8 * wave + 4 * u + (o >> 2);
            const int c = 16 * (o & 3) + 4 * g + jj;
            fold[r][c + 0] += oa[0] * rl;
            fold[r][c + 1] += oa[1] * rl;
            fold[r][c + 2] += oa[2] * rl;
            fold[r][c + 3] += oa[3] * rl;
        }

        __syncthreads();   // barrier B: this plane's KV reads done before
                           // next plane's KV write (replaces the dbuf);
                           // barrier D: fold complete before the store.
    }

    // plain coalesced store of this block's partial (NO atomics)
    float* pb = partial + ((size_t)b) * PSTRIDE;   // b = (bc*4+ii)*2+jh
    for (int i = tid; i < PSTRIDE; i += 512) {
        pb[i] = fold[i / HWDIM][i % HWDIM];
    }
}

// kernel2: out[bc][h][w] = sum over (ii,jh) of partial[bc][ii][jh][h-ii][w]
// (valid when 0 <= h-ii < 64). ~21MB traffic, memory-bound, ~3.5us.
__global__ __launch_bounds__(256) void ska_sum(
    const float* __restrict__ partial,
    float* __restrict__ out)
{
    const int idx = (int)(blockIdx.x * 256 + threadIdx.x);
    if (idx >= OUT_TOTAL) return;
    const int bc  = idx / (HWDIM * HWDIM);
    const int rem = idx % (HWDIM * HWDIM);
    const int h   = rem / HWDIM;
    const int ww  = rem % HWDIM;
    float acc = 0.f;
#pragma unroll
    for (int ii = 0; ii < 4; ++ii) {
        const int r = h - ii;
        if (r >= 0 && r < 64) {
            const size_t base = ((size_t)((bc * 4 + ii) * 2)) * PSTRIDE + r * HWDIM + ww;
            acc += partial[base] + partial[base + PSTRIDE];
        }
    }
    out[idx] = acc;
}

// ---- fallback (R17 atomic merge) if workspace is too small ----
__global__ __launch_bounds__(512, 4) void ska_fused_atomic(
    const float* __restrict__ x, const float* __restrict__ w,
    float* __restrict__ out)
{
    __shared__ __align__(16) _Float16 buf[2][16][64][8];
    __shared__ float fold[64][69];

    const int b  = (int)(blockIdx.x & 7) * 64 + (int)(blockIdx.x >> 3);
    const int bc = b >> 2;
    const int ii = b & 3;
    const int tid  = threadIdx.x;
    const int wave = tid >> 6;
    const int lane = tid & 63;
    const int o = lane & 15;
    const int g = lane >> 4;

    {
        float* ff = &fold[0][0];
        for (int i = tid; i < 64 * 69; i += 512) ff[i] = 0.f;
    }

    const float4 wq4 = *(const float4*)(w + ( 0 + o) * DIM + 4 * g);
    const float4 wk4 = *(const float4*)(w + (16 + o) * DIM + 4 * g);
    const float4 wv4 = *(const float4*)(w + (32 + o) * DIM + 4 * g);
    const half4 wqf = mk_half4(wq4.x * (ATT_SCALE * LOG2E), wq4.y * (ATT_SCALE * LOG2E),
                               wq4.z * (ATT_SCALE * LOG2E), wq4.w * (ATT_SCALE * LOG2E));
    const half4 wkf = mk_half4(wk4.x, wk4.y, wk4.z, wk4.w);
    const half4 wvf = mk_half4(wv4.x, wv4.y, wv4.z, wv4.w);
    const float4v zf = (float4v){0.f, 0.f, 0.f, 0.f};

    const float* xb = x + ((size_t)bc * HWDIM + ii) * HWDIM + (o & 3) * 16 + 4 * g;
    const int roff0 = (8 * wave + (o >> 2)) * HWDIM;
    const int roff1 = roff0 + 4 * HWDIM;

    float xr0a = xb[roff0 + 0], xr0b = xb[roff0 + 1],
          xr0c = xb[roff0 + 2], xr0d = xb[roff0 + 3];
    float xr1a = xb[roff1 + 0], xr1b = xb[roff1 + 1],
          xr1c = xb[roff1 + 2], xr1d = xb[roff1 + 3];

    for (int jj = 0; jj < 4; ++jj) {
        const int cur = jj & 1;
        half4 qfr0, qfr1;
        {
            const half4 xf0 = mk_half4(xr0a, xr0b, xr0c, xr0d);
            const half4 kf0 = pack4(__builtin_amdgcn_mfma_f32_16x16x16f16(wkf, xf0, zf, 0, 0, 0));
            const half4 vf0 = pack4(__builtin_amdgcn_mfma_f32_16x16x16f16(xf0, wvf, zf, 0, 0, 0));
            *(half8*)&buf[cur][2 * wave][lane][0] =
                __builtin_shufflevector(kf0, vf0, 0, 1, 2, 3, 4, 5, 6, 7);
            qfr0 = pack4(__builtin_amdgcn_mfma_f32_16x16x16f16(wqf, xf0, zf, 0, 0, 0));
            const half4 xf1 = mk_half4(xr1a, xr1b, xr1c, xr1d);
            const half4 kf1 = pack4(__builtin_amdgcn_mfma_f32_16x16x16f16(wkf, xf1, zf, 0, 0, 0));
            const half4 vf1 = pack4(__builtin_amdgcn_mfma_f32_16x16x16f16(xf1, wvf, zf, 0, 0, 0));
            *(half8*)&buf[cur][2 * wave + 1][lane][0] =
                __builtin_shufflevector(kf1, vf1, 0, 1, 2, 3, 4, 5, 6, 7);
            qfr1 = pack4(__builtin_amdgcn_mfma_f32_16x16x16f16(wqf, xf1, zf, 0, 0, 0));
        }
        if (jj < 3) {
            const int d = jj + 1;
            xr0a = xb[roff0 + d + 0]; xr0b = xb[roff0 + d + 1];
            xr0c = xb[roff0 + d + 2]; xr0d = xb[roff0 + d + 3];
            xr1a = xb[roff1 + d + 0]; xr1b = xb[roff1 + d + 1];
            xr1c = xb[roff1 + d + 2]; xr1d = xb[roff1 + d + 3];
        }
        __syncthreads();

        float4v oacc0 = zf, oacc1 = zf;
        float l0 = 0.f, l1 = 0.f;
        half8 kvc = *(const half8*)&buf[cur][0][lane][0];
#pragma unroll 4
        for (int t = 0; t < 16; ++t) {
            const half8 kvn = *(const half8*)&buf[cur][(t + 1) & 15][lane][0];
            const half4 kf = __builtin_shufflevector(kvc, kvc, 0, 1, 2, 3);
            const half4 vf = __builtin_shufflevector(kvc, kvc, 4, 5, 6, 7);
            const float4v s0 = __builtin_amdgcn_mfma_f32_16x16x16f16(kf, qfr0, zf, 0, 0, 0);
            const float4v s1 = __builtin_amdgcn_mfma_f32_16x16x16f16(kf, qfr1, zf, 0, 0, 0);
            att_step(vf, s0, l0, oacc0);
            att_step(vf, s1, l1, oacc1);
            kvc = kvn;
        }
#pragma unroll
        for (int u = 0; u < 2; ++u) {
            float lj = u ? l1 : l0;
            lj += __shfl_xor(lj, 16, 64);
            lj += __shfl_xor(lj, 32, 64);
            const float rl = __builtin_amdgcn_rcpf(lj);
            const float4v oa = u ? oacc1 : oacc0;
            const int r = 8 * wave + 4 * u + (o >> 2);
            const int c = 16 * (o & 3) + 4 * g + jj;
            fold[r][c + 0] += oa[0] * rl;
            fold[r][c + 1] += oa[1] * rl;
            fold[r][c + 2] += oa[2] * rl;
            fold[r][c + 3] += oa[3] * rl;
        }
    }
    __syncthreads();

    float* ob = out + ((size_t)bc * HWDIM + ii) * HWDIM;
    for (int i = tid; i < 64 * HWDIM; i += 512) {
        atomicAdd(&ob[i], fold[i / HWDIM][i % HWDIM]);
    }
}

extern "C" void kernel_launch(void* const* d_in, const int* in_sizes, int n_in,
                              void* d_out, int out_size, void* d_ws, size_t ws_size,
                              hipStream_t stream) {
    const float* x = (const float*)d_in[0];
    const float* w = (const float*)d_in[1];
    float* out = (float*)d_out;
    (void)in_sizes; (void)n_in;

    const size_t need = (size_t)BATCH * CHAN * 8 * PSTRIDE * sizeof(float); // 17.6 MB
    if (ws_size >= need) {
        float* partial = (float*)d_ws;
        ska_part<<<BATCH * CHAN * 8, 512, 0, stream>>>(x, w, partial);
        ska_sum<<<(OUT_TOTAL + 255) / 256, 256, 0, stream>>>(partial, out);
    } else {
        (void)hipMemsetAsync(out, 0, (size_t)out_size * sizeof(float), stream);
        ska_fused_atomic<<<BATCH * CHAN * 4, 512, 0, stream>>>(x, w, out);
    }
}